// Round 11
// baseline (524.664 us; speedup 1.0000x reference)
//
#include <hip/hip_runtime.h>
#include <hip/hip_bf16.h>

#define D_MODEL 1024
#define NHEAD 16
#define DH 64
#define DFF 4096
#define MAXD 32
#define L_ 2048
#define NROW 4096

typedef __attribute__((ext_vector_type(4))) float floatx4;
typedef __attribute__((ext_vector_type(8))) __bf16 bf16x8;
typedef __attribute__((ext_vector_type(4))) unsigned short ushort4v;

static __device__ inline unsigned short f2bf(float f) {
    __hip_bfloat16 h = __float2bfloat16(f);
    return __builtin_bit_cast(unsigned short, h);
}

static __device__ inline floatx4 mfma16(bf16x8 a, bf16x8 b, floatx4 c) {
    return __builtin_amdgcn_mfma_f32_16x16x32_bf16(a, b, c, 0, 0, 0);
}

static __device__ inline void gload_lds16(const unsigned short* g, unsigned short* l) {
    __builtin_amdgcn_global_load_lds((const __attribute__((address_space(1))) unsigned int*)g,
                                     (__attribute__((address_space(3))) unsigned int*)l,
                                     16, 0, 0);
}

// ---------------- elementwise cast fp32 -> bf16 ----------------
__global__ __launch_bounds__(256) void cast_bf16_kernel(const float* __restrict__ in,
                                                        unsigned short* __restrict__ out, int n4) {
    int i = blockIdx.x * 256 + threadIdx.x;
    if (i < n4) {
        floatx4 v = *(const floatx4*)&in[(size_t)i * 4];
        ushort4v o;
        o.x = f2bf(v[0]); o.y = f2bf(v[1]); o.z = f2bf(v[2]); o.w = f2bf(v[3]);
        *(ushort4v*)&out[(size_t)i * 4] = o;
    }
}

// ---------------- transpose + cast: W fp32 [K][N] -> WT bf16 [N][K] ----------------
__global__ __launch_bounds__(256) void transpose_cast_kernel(const float* __restrict__ W,
                                                             unsigned short* __restrict__ WT,
                                                             int K, int N) {
    __shared__ float tile[32][33];
    int k0 = blockIdx.y * 32, n0 = blockIdx.x * 32;
    for (int i = threadIdx.x; i < 1024; i += 256) {
        int r = i >> 5, c = i & 31;
        tile[r][c] = W[(size_t)(k0 + r) * N + n0 + c];
    }
    __syncthreads();
    for (int i = threadIdx.x; i < 1024; i += 256) {
        int r = i >> 5, c = i & 31;
        WT[(size_t)(n0 + r) * K + k0 + c] = f2bf(tile[c][r]);
    }
}

// ---------------- pack qkv bias ----------------
__global__ __launch_bounds__(256) void pack_bias_kernel(const float* __restrict__ bq,
                                                        const float* __restrict__ bk,
                                                        const float* __restrict__ bv,
                                                        float* __restrict__ out) {
    int i = blockIdx.x * 256 + threadIdx.x;
    if (i < 3072) out[i] = (i < 1024) ? bq[i] : ((i < 2048) ? bk[i - 1024] : bv[i - 2048]);
}

// ---------------- GEMM: C[M][N] = A[M][K] @ BT[N][K]^T + bias ----------------
// Round-9 proven: BK=64, chunk-XOR LDS swizzle, bijective XCD block swizzle.
template <int NF, bool OUTBF16, bool RELU>
__global__ __launch_bounds__(256) void gemm_kernel(const unsigned short* __restrict__ A,
                                                   const unsigned short* __restrict__ BT,
                                                   const float* __restrict__ bias,
                                                   void* __restrict__ Cout,
                                                   int M, int N, int K, int gx) {
    constexpr int BN = NF * 32;
    __shared__ unsigned short Asm[128][64];
    __shared__ unsigned short Bsm[BN][64];
    int t = threadIdx.x;
    int lane = t & 63, w = t >> 6;
    int wm = w >> 1, wn = w & 1;
    int lr = lane & 15, hg = lane >> 4;

    int nwg = gridDim.x;
    int bid = blockIdx.x;
    int id = (bid & 7) * (nwg >> 3) + (bid >> 3);   // bijective (nwg % 8 == 0)
    int m0 = (id / gx) * 128, n0 = (id % gx) * BN;

    floatx4 acc[4][NF];
#pragma unroll
    for (int i = 0; i < 4; i++)
#pragma unroll
        for (int j = 0; j < NF; j++) acc[i][j] = (floatx4)0.0f;

    const int lr7 = lr & 7;

    for (int k0 = 0; k0 < K; k0 += 64) {
        __syncthreads();
#pragma unroll
        for (int i = 0; i < 4; i++) {
            int c = t + i * 256;               // 1024 chunks: 128 rows x 8
            int r = c >> 3, ch = c & 7;
            int chs = ch ^ (r & 7);
            gload_lds16(&A[(size_t)(m0 + r) * K + k0 + chs * 8], &Asm[r][ch * 8]);
        }
#pragma unroll
        for (int i = 0; i < BN / 32; i++) {    // BN*8 chunks
            int c = t + i * 256;
            int r = c >> 3, ch = c & 7;
            int chs = ch ^ (r & 7);
            gload_lds16(&BT[(size_t)(n0 + r) * K + k0 + chs * 8], &Bsm[r][ch * 8]);
        }
        __syncthreads();
#pragma unroll
        for (int kc = 0; kc < 2; kc++) {
            int ch = (kc * 4 + hg) ^ lr7;
            bf16x8 af[4], bfg[NF];
#pragma unroll
            for (int mf = 0; mf < 4; mf++)
                af[mf] = *(const bf16x8*)&Asm[wm * 64 + mf * 16 + lr][ch * 8];
#pragma unroll
            for (int nf = 0; nf < NF; nf++)
                bfg[nf] = *(const bf16x8*)&Bsm[wn * NF * 16 + nf * 16 + lr][ch * 8];
#pragma unroll
            for (int mf = 0; mf < 4; mf++)
#pragma unroll
                for (int nf = 0; nf < NF; nf++) acc[mf][nf] = mfma16(af[mf], bfg[nf], acc[mf][nf]);
        }
    }

#pragma unroll
    for (int mf = 0; mf < 4; mf++)
#pragma unroll
        for (int nf = 0; nf < NF; nf++) {
            int col = n0 + wn * NF * 16 + nf * 16 + lr;
            float bv = bias[col];
#pragma unroll
            for (int r = 0; r < 4; r++) {
                int row = m0 + wm * 64 + mf * 16 + hg * 4 + r;
                float v = acc[mf][nf][r] + bv;
                if (RELU) v = v > 0.f ? v : 0.f;
                if (OUTBF16)
                    ((unsigned short*)Cout)[(size_t)row * N + col] = f2bf(v);
                else
                    ((float*)Cout)[(size_t)row * N + col] = v;
            }
        }
}

// ---------------- fused attention, swapped-QK^T / in-lane softmax ----------------
// r6 staging/barrier skeleton, but each wave owns TWO q-fragments (32 q-cols) ->
// 2x MFMA+softmax per iteration amortizes the fixed per-iter stalls. 256 blocks x
// 512 threads (q-span 256/block). Ps (wave-private) time-shared: softmaxA -> write
// -> PV-A -> write-B -> PV-B (same-wave LDS ordering, no extra barrier).
__global__ __launch_bounds__(512, 4) void attn_kernel(const unsigned short* __restrict__ qkv, // [4096][3072]
                                                      const float* __restrict__ rpe,          // [65][16]
                                                      unsigned short* __restrict__ ctx) {     // [4096][1024]
    __shared__ unsigned short Kb0[64 * 64];
    __shared__ unsigned short Kb1[64 * 64];
    __shared__ unsigned short Vt[64 * 64];      // V^T: [d][k_local], chunk-XOR swizzled
    __shared__ unsigned short Ps[8][16 * 64];   // per-wave P^T tile, time-shared A/B
    __shared__ float rpl[65];

    const int t = threadIdx.x;
    const int lane = t & 63, w = t >> 6;
    const int lr = lane & 15, hg = lane >> 4;
    const int lrs = (lr & 7) ^ (lr >> 3);

    const int g = blockIdx.x;
    const int blk = (g & 7) * 32 + (g >> 3);    // bijective XCD-chunk swizzle (256 = 8*32)
    const int qb = blk & 7;
    const int h = (blk >> 3) & 15;
    const int b = blk >> 7;
    const int q0 = qb * 256;
    const int hcol = h * 64;
    const size_t rowbase = (size_t)b * L_ * 3072;

    const int kr = t >> 3, kch = t & 7;
    const int kswz = (kch ^ (kr & 7) ^ (kr >> 3)) & 7;
    unsigned short* kdst0 = &Kb0[kr * 64 + kch * 8];
    unsigned short* kdst1 = &Kb1[kr * 64 + kch * 8];

    if (t < 65) rpl[t] = rpe[t * NHEAD + h];

    const int qiA = q0 + w * 32 + lr;
    const int qiB = qiA + 16;
    bf16x8 qfA0 = *(const bf16x8*)&qkv[rowbase + (size_t)qiA * 3072 + hcol + hg * 8];
    bf16x8 qfA1 = *(const bf16x8*)&qkv[rowbase + (size_t)qiA * 3072 + hcol + 32 + hg * 8];
    bf16x8 qfB0 = *(const bf16x8*)&qkv[rowbase + (size_t)qiB * 3072 + hcol + hg * 8];
    bf16x8 qfB1 = *(const bf16x8*)&qkv[rowbase + (size_t)qiB * 3072 + hcol + 32 + hg * 8];

    gload_lds16(&qkv[rowbase + (size_t)kr * 3072 + 1024 + hcol + kswz * 8], kdst0);
    __syncthreads();

    float rpl0 = rpl[0], rpl64 = rpl[64];
    floatx4 oA[4], oB[4];
#pragma unroll
    for (int df = 0; df < 4; df++) { oA[df] = (floatx4)0.f; oB[df] = (floatx4)0.f; }
    float mstA = -1e30f, lstA = 0.f, mstB = -1e30f, lstB = 0.f;
    const float scale = 0.125f;
    unsigned short* PsW = &Ps[w][0];

#define ATT_STEP(KT, KcP, KnP, MORE)                                                               \
    {                                                                                              \
        const int key0 = (KT) * 64;                                                                \
        int4 tv = *(const int4*)&qkv[rowbase + (size_t)(key0 + kr) * 3072 + 2048 + hcol + kch * 8];\
        if (MORE)                                                                                  \
            gload_lds16(&qkv[rowbase + (size_t)(key0 + 64 + kr) * 3072 + 1024 + hcol + kswz * 8],  \
                        KnP);                                                                      \
        floatx4 stA[4], stB[4];                                                                    \
        _Pragma("unroll")                                                                          \
        for (int kf = 0; kf < 4; kf++) {                                                           \
            int sw = lrs ^ (kf * 2);                                                               \
            bf16x8 a0 = *(const bf16x8*)&(KcP)[(kf * 16 + lr) * 64 + ((hg ^ sw) << 3)];            \
            bf16x8 a1 = *(const bf16x8*)&(KcP)[(kf * 16 + lr) * 64 + (((4 + hg) ^ sw) << 3)];      \
            stA[kf] = mfma16(a1, qfA1, mfma16(a0, qfA0, (floatx4)0.f));                            \
            stB[kf] = mfma16(a1, qfB1, mfma16(a0, qfB0, (floatx4)0.f));                            \
        }                                                                                          \
        bool rightC = (key0 > q0 + 287);                                                           \
        bool leftC = (key0 + 95 < q0);                                                             \
        bool ccp = leftC || rightC;                                                                \
        float cbv = rightC ? rpl64 : rpl0;                                                         \
        unsigned int pk1[8];                                                                       \
        /* softmax fragment A -> Ps */                                                             \
        {                                                                                          \
            float sv[16];                                                                          \
            float mx = -1e30f;                                                                     \
            if (ccp) {                                                                             \
                _Pragma("unroll")                                                                  \
                for (int kf = 0; kf < 4; kf++)                                                     \
                    _Pragma("unroll")                                                              \
                    for (int r = 0; r < 4; r++) {                                                  \
                        float v = stA[kf][r] * scale + cbv;                                        \
                        sv[kf * 4 + r] = v;                                                        \
                        mx = fmaxf(mx, v);                                                         \
                    }                                                                              \
            } else {                                                                               \
                _Pragma("unroll")                                                                  \
                for (int kf = 0; kf < 4; kf++)                                                     \
                    _Pragma("unroll")                                                              \
                    for (int r = 0; r < 4; r++) {                                                  \
                        int rel = key0 + kf * 16 + hg * 4 + r - qiA;                               \
                        rel = rel < -MAXD ? -MAXD : (rel > MAXD ? MAXD : rel);                     \
                        float v = stA[kf][r] * scale + rpl[rel + MAXD];                            \
                        sv[kf * 4 + r] = v;                                                        \
                        mx = fmaxf(mx, v);                                                         \
                    }                                                                              \
            }                                                                                      \
            mx = fmaxf(mx, __shfl_xor(mx, 16, 64));                                                \
            mx = fmaxf(mx, __shfl_xor(mx, 32, 64));                                                \
            float newm = fmaxf(mstA, mx);                                                          \
            float corr = __expf(mstA - newm);                                                      \
            mstA = newm;                                                                           \
            float ps = 0.f;                                                                        \
            _Pragma("unroll")                                                                      \
            for (int kf = 0; kf < 4; kf++)                                                         \
                _Pragma("unroll")                                                                  \
                for (int j = 0; j < 2; j++) {                                                      \
                    float p0 = __expf(sv[kf * 4 + 2 * j] - newm);                                  \
                    float p1 = __expf(sv[kf * 4 + 2 * j + 1] - newm);                              \
                    ps += p0 + p1;                                                                 \
                    unsigned int pk = (unsigned int)f2bf(p0) | ((unsigned int)f2bf(p1) << 16);     \
                    int ch = ((kf * 2 + (hg >> 1)) ^ lrs) & 7;                                     \
                    *(unsigned int*)&PsW[lr * 64 + (ch << 3) + (hg & 1) * 4 + 2 * j] = pk;         \
                }                                                                                  \
            lstA = lstA * corr + ps;                                                               \
            _Pragma("unroll")                                                                      \
            for (int df = 0; df < 4; df++) oA[df] *= corr;                                         \
        }                                                                                          \
        /* softmax fragment B -> registers (Ps busy with A) */                                     \
        {                                                                                          \
            float sv[16];                                                                          \
            float mx = -1e30f;                                                                     \
            if (ccp) {                                                                             \
                _Pragma("unroll")                                                                  \
                for (int kf = 0; kf < 4; kf++)                                                     \
                    _Pragma("unroll")                                                              \
                    for (int r = 0; r < 4; r++) {                                                  \
                        float v = stB[kf][r] * scale + cbv;                                        \
                        sv[kf * 4 + r] = v;                                                        \
                        mx = fmaxf(mx, v);                                                         \
                    }                                                                              \
            } else {                                                                               \
                _Pragma("unroll")                                                                  \
                for (int kf = 0; kf < 4; kf++)                                                     \
                    _Pragma("unroll")                                                              \
                    for (int r = 0; r < 4; r++) {                                                  \
                        int rel = key0 + kf * 16 + hg * 4 + r - qiB;                               \
                        rel = rel < -MAXD ? -MAXD : (rel > MAXD ? MAXD : rel);                     \
                        float v = stB[kf][r] * scale + rpl[rel + MAXD];                            \
                        sv[kf * 4 + r] = v;                                                        \
                        mx = fmaxf(mx, v);                                                         \
                    }                                                                              \
            }                                                                                      \
            mx = fmaxf(mx, __shfl_xor(mx, 16, 64));                                                \
            mx = fmaxf(mx, __shfl_xor(mx, 32, 64));                                                \
            float newm = fmaxf(mstB, mx);                                                          \
            float corr = __expf(mstB - newm);                                                      \
            mstB = newm;                                                                           \
            float ps = 0.f;                                                                        \
            _Pragma("unroll")                                                                      \
            for (int kf = 0; kf < 4; kf++)                                                         \
                _Pragma("unroll")                                                                  \
                for (int j = 0; j < 2; j++) {                                                      \
                    float p0 = __expf(sv[kf * 4 + 2 * j] - newm);                                  \
                    float p1 = __expf(sv[kf * 4 + 2 * j + 1] - newm);                              \
                    ps += p0 + p1;                                                                 \
                    pk1[kf * 2 + j] = (unsigned int)f2bf(p0) | ((unsigned int)f2bf(p1) << 16);     \
                }                                                                                  \
            lstB = lstB * corr + ps;                                                               \
            _Pragma("unroll")                                                                      \
            for (int df = 0; df < 4; df++) oB[df] *= corr;                                         \
        }                                                                                          \
        /* V transpose-write, then block-wide rendezvous */                                        \
        _Pragma("unroll")                                                                          \
        for (int e = 0; e < 8; e++) {                                                              \
            int d = kch * 8 + e;                                                                   \
            int ch = ((kr >> 3) ^ e ^ kch) & 7;                                                    \
            unsigned short val = (unsigned short)(((const unsigned int*)&tv)[e >> 1] >>            \
                                                  ((e & 1) * 16));                                 \
            Vt[d * 64 + (ch << 3) + (kr & 7)] = val;                                               \
        }                                                                                          \
        __syncthreads();                                                                           \
        /* PV fragment A */                                                                        \
        {                                                                                          \
            bf16x8 pb0 = *(const bf16x8*)&PsW[lr * 64 + ((hg ^ lrs) << 3)];                        \
            bf16x8 pb1 = *(const bf16x8*)&PsW[lr * 64 + (((4 + hg) ^ lrs) << 3)];                  \
            _Pragma("unroll")                                                                      \
            for (int df = 0; df < 4; df++) {                                                       \
                int sw = lrs ^ (df * 2);                                                           \
                bf16x8 v0 = *(const bf16x8*)&Vt[(df * 16 + lr) * 64 + ((hg ^ sw) << 3)];           \
                bf16x8 v1 = *(const bf16x8*)&Vt[(df * 16 + lr) * 64 + (((4 + hg) ^ sw) << 3)];     \
                oA[df] = mfma16(v1, pb1, mfma16(v0, pb0, oA[df]));                                 \
            }                                                                                      \
        }                                                                                          \
        /* write fragment B's P (wave-private; same-wave LDS ordering vs reads above) */           \
        _Pragma("unroll")                                                                          \
        for (int kf = 0; kf < 4; kf++)                                                             \
            _Pragma("unroll")                                                                      \
            for (int j = 0; j < 2; j++) {                                                          \
                int ch = ((kf * 2 + (hg >> 1)) ^ lrs) & 7;                                         \
                *(unsigned int*)&PsW[lr * 64 + (ch << 3) + (hg & 1) * 4 + 2 * j] = pk1[kf * 2 + j];\
            }                                                                                      \
        /* PV fragment B */                                                                        \
        {                                                                                          \
            bf16x8 pb0 = *(const bf16x8*)&PsW[lr * 64 + ((hg ^ lrs) << 3)];                        \
            bf16x8 pb1 = *(const bf16x8*)&PsW[lr * 64 + (((4 + hg) ^ lrs) << 3)];                  \
            _Pragma("unroll")                                                                      \
            for (int df = 0; df < 4; df++) {                                                       \
                int sw = lrs ^ (df * 2);                                                           \
                bf16x8 v0 = *(const bf16x8*)&Vt[(df * 16 + lr) * 64 + ((hg ^ sw) << 3)];           \
                bf16x8 v1 = *(const bf16x8*)&Vt[(df * 16 + lr) * 64 + (((4 + hg) ^ sw) << 3)];     \
                oB[df] = mfma16(v1, pb1, mfma16(v0, pb0, oB[df]));                                 \
            }                                                                                      \
        }                                                                                          \
        __syncthreads();                                                                           \
    }

    for (int kt = 0; kt < L_ / 64; kt += 2) {
        ATT_STEP(kt, Kb0, kdst1, true);
        ATT_STEP(kt + 1, Kb1, kdst0, (kt + 2 < L_ / 64));
    }
#undef ATT_STEP

    {
        float rs = lstA;
        rs += __shfl_xor(rs, 16, 64);
        rs += __shfl_xor(rs, 32, 64);
        float inv = 1.f / rs;
        size_t obase = (size_t)(b * L_ + qiA) * 1024 + hcol;
#pragma unroll
        for (int df = 0; df < 4; df++)
#pragma unroll
            for (int r = 0; r < 4; r++)
                ctx[obase + df * 16 + hg * 4 + r] = f2bf(oA[df][r] * inv);
    }
    {
        float rs = lstB;
        rs += __shfl_xor(rs, 16, 64);
        rs += __shfl_xor(rs, 32, 64);
        float inv = 1.f / rs;
        size_t obase = (size_t)(b * L_ + qiB) * 1024 + hcol;
#pragma unroll
        for (int df = 0; df < 4; df++)
#pragma unroll
            for (int r = 0; r < 4; r++)
                ctx[obase + df * 16 + hg * 4 + r] = f2bf(oB[df][r] * inv);
    }
}

// ---------------- fused residual + layernorm ----------------
template <bool WBF>
__global__ __launch_bounds__(256) void resln_kernel(const float* __restrict__ ra,
                                                    const float* __restrict__ rb,
                                                    const float* __restrict__ g,
                                                    const float* __restrict__ be,
                                                    float* __restrict__ outf,
                                                    unsigned short* __restrict__ outb) {
    __shared__ float red[4];
    __shared__ float red2[4];
    int row = blockIdx.x;
    int t = threadIdx.x;
    int w = t >> 6, lane = t & 63;
    size_t base = (size_t)row * 1024 + t * 4;
    floatx4 a = *(const floatx4*)&ra[base];
    floatx4 b = *(const floatx4*)&rb[base];
    floatx4 y = a + b;
    float s = y[0] + y[1] + y[2] + y[3];
#pragma unroll
    for (int d = 1; d < 64; d <<= 1) s += __shfl_xor(s, d, 64);
    if (lane == 0) red[w] = s;
    __syncthreads();
    float mu = (red[0] + red[1] + red[2] + red[3]) * (1.f / 1024.f);
    floatx4 d4 = y - mu;
    float sq = d4[0] * d4[0] + d4[1] * d4[1] + d4[2] * d4[2] + d4[3] * d4[3];
#pragma unroll
    for (int d = 1; d < 64; d <<= 1) sq += __shfl_xor(sq, d, 64);
    if (lane == 0) red2[w] = sq;
    __syncthreads();
    float var = (red2[0] + red2[1] + red2[2] + red2[3]) * (1.f / 1024.f);
    float rstd = rsqrtf(var + 1e-5f);
    floatx4 gg = *(const floatx4*)&g[t * 4];
    floatx4 bb = *(const floatx4*)&be[t * 4];
    floatx4 outv;
#pragma unroll
    for (int i = 0; i < 4; i++) outv[i] = d4[i] * rstd * gg[i] + bb[i];
    *(floatx4*)&outf[base] = outv;
    if (WBF) {
        ushort4v ov;
        ov.x = f2bf(outv[0]); ov.y = f2bf(outv[1]); ov.z = f2bf(outv[2]); ov.w = f2bf(outv[3]);
        *(ushort4v*)&outb[base] = ov;
    }
}

extern "C" void kernel_launch(void* const* d_in, const int* in_sizes, int n_in,
                              void* d_out, int out_size, void* d_ws, size_t ws_size,
                              hipStream_t stream) {
    const float* src = (const float*)d_in[0];
    const float* Wq = (const float*)d_in[1];
    const float* Wk = (const float*)d_in[2];
    const float* Wv = (const float*)d_in[3];
    const float* bq = (const float*)d_in[4];
    const float* bk = (const float*)d_in[5];
    const float* bv = (const float*)d_in[6];
    const float* Wo = (const float*)d_in[7];
    const float* bo = (const float*)d_in[8];
    const float* rpe = (const float*)d_in[9];
    const float* W1 = (const float*)d_in[10];
    const float* b1 = (const float*)d_in[11];
    const float* W2 = (const float*)d_in[12];
    const float* b2 = (const float*)d_in[13];
    const float* ln1g = (const float*)d_in[14];
    const float* ln1b = (const float*)d_in[15];
    const float* ln2g = (const float*)d_in[16];
    const float* ln2b = (const float*)d_in[17];
    float* out = (float*)d_out;
    char* ws = (char*)d_ws;

    const size_t o_srcb = 0;                       // 8 MB   bf16 src; later reused as xb
    const size_t o_wtqkv = o_srcb + 8388608;       // 6 MB
    const size_t o_wto = o_wtqkv + 6291456;        // 2 MB
    const size_t o_wt1 = o_wto + 2097152;          // 8 MB
    const size_t o_wt2 = o_wt1 + 8388608;          // 8 MB
    const size_t o_bqkv = o_wt2 + 8388608;         // 12 KB
    const size_t o_qkv = o_bqkv + 12288;           // 24 MB  qkv bf16; later reused as attnout/ff fp32
    const size_t o_ctxb = o_qkv + 25165824;        // 8 MB
    const size_t o_x = o_ctxb + 8388608;           // 16 MB
    const size_t o_hb = o_x + 16777216;            // 32 MB

    unsigned short* srcb = (unsigned short*)(ws + o_srcb);
    unsigned short* wtqkv = (unsigned short*)(ws + o_wtqkv);
    unsigned short* wto = (unsigned short*)(ws + o_wto);
    unsigned short* wt1 = (unsigned short*)(ws + o_wt1);
    unsigned short* wt2 = (unsigned short*)(ws + o_wt2);
    float* bqkv = (float*)(ws + o_bqkv);
    unsigned short* qkvb = (unsigned short*)(ws + o_qkv);
    unsigned short* ctxb = (unsigned short*)(ws + o_ctxb);
    float* x = (float*)(ws + o_x);
    unsigned short* hb = (unsigned short*)(ws + o_hb);
    float* attnout = (float*)(ws + o_qkv);
    float* ff = (float*)(ws + o_qkv);
    unsigned short* xb = (unsigned short*)(ws + o_srcb);

    cast_bf16_kernel<<<4096, 256, 0, stream>>>(src, srcb, 1048576);
    transpose_cast_kernel<<<dim3(32, 32), 256, 0, stream>>>(Wq, wtqkv, 1024, 1024);
    transpose_cast_kernel<<<dim3(32, 32), 256, 0, stream>>>(Wk, wtqkv + 1024 * 1024, 1024, 1024);
    transpose_cast_kernel<<<dim3(32, 32), 256, 0, stream>>>(Wv, wtqkv + 2 * 1024 * 1024, 1024, 1024);
    transpose_cast_kernel<<<dim3(32, 32), 256, 0, stream>>>(Wo, wto, 1024, 1024);
    transpose_cast_kernel<<<dim3(128, 32), 256, 0, stream>>>(W1, wt1, 1024, 4096);
    transpose_cast_kernel<<<dim3(32, 128), 256, 0, stream>>>(W2, wt2, 4096, 1024);
    pack_bias_kernel<<<12, 256, 0, stream>>>(bq, bk, bv, bqkv);

    gemm_kernel<4, true, false><<<768, 256, 0, stream>>>(srcb, wtqkv, bqkv, qkvb, NROW, 3072, 1024, 24);
    attn_kernel<<<256, 512, 0, stream>>>(qkvb, rpe, ctxb);
    gemm_kernel<2, false, false><<<512, 256, 0, stream>>>(ctxb, wto, bo, attnout, NROW, 1024, 1024, 16);
    resln_kernel<true><<<4096, 256, 0, stream>>>(src, attnout, ln1g, ln1b, x, xb);
    gemm_kernel<4, true, true><<<1024, 256, 0, stream>>>(xb, wt1, b1, hb, NROW, 4096, 1024, 32);
    gemm_kernel<2, false, false><<<512, 256, 0, stream>>>(hb, wt2, b2, ff, NROW, 1024, 4096, 16);
    resln_kernel<false><<<4096, 256, 0, stream>>>(x, ff, ln2g, ln2b, out, nullptr);
}

// Round 12
// 305.484 us; speedup vs baseline: 1.7175x; 1.7175x over previous
//
#include <hip/hip_runtime.h>
#include <hip/hip_bf16.h>

#define D_MODEL 1024
#define NHEAD 16
#define DH 64
#define DFF 4096
#define MAXD 32
#define L_ 2048
#define NROW 4096

typedef __attribute__((ext_vector_type(4))) float floatx4;
typedef __attribute__((ext_vector_type(8))) __bf16 bf16x8;
typedef __attribute__((ext_vector_type(4))) unsigned short ushort4v;

static __device__ inline unsigned short f2bf(float f) {
    __hip_bfloat16 h = __float2bfloat16(f);
    return __builtin_bit_cast(unsigned short, h);
}

static __device__ inline floatx4 mfma16(bf16x8 a, bf16x8 b, floatx4 c) {
    return __builtin_amdgcn_mfma_f32_16x16x32_bf16(a, b, c, 0, 0, 0);
}

static __device__ inline void gload_lds16(const unsigned short* g, unsigned short* l) {
    __builtin_amdgcn_global_load_lds((const __attribute__((address_space(1))) unsigned int*)g,
                                     (__attribute__((address_space(3))) unsigned int*)l,
                                     16, 0, 0);
}

// ---------------- elementwise cast fp32 -> bf16 ----------------
__global__ __launch_bounds__(256) void cast_bf16_kernel(const float* __restrict__ in,
                                                        unsigned short* __restrict__ out, int n4) {
    int i = blockIdx.x * 256 + threadIdx.x;
    if (i < n4) {
        floatx4 v = *(const floatx4*)&in[(size_t)i * 4];
        ushort4v o;
        o.x = f2bf(v[0]); o.y = f2bf(v[1]); o.z = f2bf(v[2]); o.w = f2bf(v[3]);
        *(ushort4v*)&out[(size_t)i * 4] = o;
    }
}

// ---------------- transpose + cast: W fp32 [K][N] -> WT bf16 [N][K] ----------------
__global__ __launch_bounds__(256) void transpose_cast_kernel(const float* __restrict__ W,
                                                             unsigned short* __restrict__ WT,
                                                             int K, int N) {
    __shared__ float tile[32][33];
    int k0 = blockIdx.y * 32, n0 = blockIdx.x * 32;
    for (int i = threadIdx.x; i < 1024; i += 256) {
        int r = i >> 5, c = i & 31;
        tile[r][c] = W[(size_t)(k0 + r) * N + n0 + c];
    }
    __syncthreads();
    for (int i = threadIdx.x; i < 1024; i += 256) {
        int r = i >> 5, c = i & 31;
        WT[(size_t)(n0 + r) * K + k0 + c] = f2bf(tile[c][r]);
    }
}

// ---------------- pack qkv bias ----------------
__global__ __launch_bounds__(256) void pack_bias_kernel(const float* __restrict__ bq,
                                                        const float* __restrict__ bk,
                                                        const float* __restrict__ bv,
                                                        float* __restrict__ out) {
    int i = blockIdx.x * 256 + threadIdx.x;
    if (i < 3072) out[i] = (i < 1024) ? bq[i] : ((i < 2048) ? bk[i - 1024] : bv[i - 2048]);
}

// ---------------- GEMM: C[M][N] = A[M][K] @ BT[N][K]^T + bias ----------------
// BK=64, chunk-XOR LDS swizzle (chunk' = chunk ^ (row&7), pre-swizzled global source,
// linear gload_lds dest), bijective XCD block swizzle (nwg % 8 == 0).
template <int NF, bool OUTBF16, bool RELU>
__global__ __launch_bounds__(256) void gemm_kernel(const unsigned short* __restrict__ A,
                                                   const unsigned short* __restrict__ BT,
                                                   const float* __restrict__ bias,
                                                   void* __restrict__ Cout,
                                                   int M, int N, int K, int gx) {
    constexpr int BN = NF * 32;
    __shared__ unsigned short Asm[128][64];
    __shared__ unsigned short Bsm[BN][64];
    int t = threadIdx.x;
    int lane = t & 63, w = t >> 6;
    int wm = w >> 1, wn = w & 1;
    int lr = lane & 15, hg = lane >> 4;

    int nwg = gridDim.x;
    int bid = blockIdx.x;
    int id = (bid & 7) * (nwg >> 3) + (bid >> 3);   // bijective (nwg % 8 == 0)
    int m0 = (id / gx) * 128, n0 = (id % gx) * BN;

    floatx4 acc[4][NF];
#pragma unroll
    for (int i = 0; i < 4; i++)
#pragma unroll
        for (int j = 0; j < NF; j++) acc[i][j] = (floatx4)0.0f;

    const int lr7 = lr & 7;

    for (int k0 = 0; k0 < K; k0 += 64) {
        __syncthreads();
#pragma unroll
        for (int i = 0; i < 4; i++) {
            int c = t + i * 256;               // 1024 chunks: 128 rows x 8
            int r = c >> 3, ch = c & 7;
            int chs = ch ^ (r & 7);
            gload_lds16(&A[(size_t)(m0 + r) * K + k0 + chs * 8], &Asm[r][ch * 8]);
        }
#pragma unroll
        for (int i = 0; i < BN / 32; i++) {    // BN*8 chunks
            int c = t + i * 256;
            int r = c >> 3, ch = c & 7;
            int chs = ch ^ (r & 7);
            gload_lds16(&BT[(size_t)(n0 + r) * K + k0 + chs * 8], &Bsm[r][ch * 8]);
        }
        __syncthreads();
#pragma unroll
        for (int kc = 0; kc < 2; kc++) {
            int ch = (kc * 4 + hg) ^ lr7;
            bf16x8 af[4], bfg[NF];
#pragma unroll
            for (int mf = 0; mf < 4; mf++)
                af[mf] = *(const bf16x8*)&Asm[wm * 64 + mf * 16 + lr][ch * 8];
#pragma unroll
            for (int nf = 0; nf < NF; nf++)
                bfg[nf] = *(const bf16x8*)&Bsm[wn * NF * 16 + nf * 16 + lr][ch * 8];
#pragma unroll
            for (int mf = 0; mf < 4; mf++)
#pragma unroll
                for (int nf = 0; nf < NF; nf++) acc[mf][nf] = mfma16(af[mf], bfg[nf], acc[mf][nf]);
        }
    }

#pragma unroll
    for (int mf = 0; mf < 4; mf++)
#pragma unroll
        for (int nf = 0; nf < NF; nf++) {
            int col = n0 + wn * NF * 16 + nf * 16 + lr;
            float bv = bias[col];
#pragma unroll
            for (int r = 0; r < 4; r++) {
                int row = m0 + wm * 64 + mf * 16 + hg * 4 + r;
                float v = acc[mf][nf][r] + bv;
                if (RELU) v = v > 0.f ? v : 0.f;
                if (OUTBF16)
                    ((unsigned short*)Cout)[(size_t)row * N + col] = f2bf(v);
                else
                    ((float*)Cout)[(size_t)row * N + col] = v;
            }
        }
}

// ---------------- fused attention, swapped-QK^T / in-lane softmax ----------------
// Proven 104 us configuration (round 6/10): 512x512, K dbuf, single Vt, 2 barriers/
// iter, XCD-chunk block swizzle, __expf softmax, one q-fragment per wave.
__global__ __launch_bounds__(512, 4) void attn_kernel(const unsigned short* __restrict__ qkv, // [4096][3072]
                                                      const float* __restrict__ rpe,          // [65][16]
                                                      unsigned short* __restrict__ ctx) {     // [4096][1024]
    __shared__ unsigned short Kb0[64 * 64];
    __shared__ unsigned short Kb1[64 * 64];
    __shared__ unsigned short Vt[64 * 64];      // V^T: [d][k_local], chunk-XOR swizzled
    __shared__ unsigned short Ps[8][16 * 64];   // per-wave P^T as [q][k_local]
    __shared__ float rpl[65];

    const int t = threadIdx.x;
    const int lane = t & 63, w = t >> 6;
    const int lr = lane & 15, hg = lane >> 4;
    const int lrs = (lr & 7) ^ (lr >> 3);

    const int g = blockIdx.x;
    const int blk = (g & 7) * 64 + (g >> 3);    // bijective XCD-chunk swizzle (512 = 8*64)
    const int qb = blk & 15;
    const int h = (blk >> 4) & 15;
    const int b = blk >> 8;
    const int q0 = qb * 128;
    const int hcol = h * 64;
    const size_t rowbase = (size_t)b * L_ * 3072;

    const int kr = t >> 3, kch = t & 7;
    const int kswz = (kch ^ (kr & 7) ^ (kr >> 3)) & 7;
    unsigned short* kdst0 = &Kb0[kr * 64 + kch * 8];
    unsigned short* kdst1 = &Kb1[kr * 64 + kch * 8];

    if (t < 65) rpl[t] = rpe[t * NHEAD + h];

    const int qi = q0 + w * 16 + lr;
    bf16x8 qf0 = *(const bf16x8*)&qkv[rowbase + (size_t)qi * 3072 + hcol + hg * 8];
    bf16x8 qf1 = *(const bf16x8*)&qkv[rowbase + (size_t)qi * 3072 + hcol + 32 + hg * 8];

    gload_lds16(&qkv[rowbase + (size_t)kr * 3072 + 1024 + hcol + kswz * 8], kdst0);
    __syncthreads();

    float rpl0 = rpl[0], rpl64 = rpl[64];
    floatx4 o[4];
#pragma unroll
    for (int df = 0; df < 4; df++) o[df] = (floatx4)0.f;
    float mst = -1e30f, lst = 0.f;
    const float scale = 0.125f;
    unsigned short* PsW = &Ps[w][0];

#define ATT_STEP(KT, KcP, KnP, MORE)                                                               \
    {                                                                                              \
        const int key0 = (KT) * 64;                                                                \
        int4 tv = *(const int4*)&qkv[rowbase + (size_t)(key0 + kr) * 3072 + 2048 + hcol + kch * 8];\
        if (MORE)                                                                                  \
            gload_lds16(&qkv[rowbase + (size_t)(key0 + 64 + kr) * 3072 + 1024 + hcol + kswz * 8],  \
                        KnP);                                                                      \
        floatx4 st[4];                                                                             \
        _Pragma("unroll")                                                                          \
        for (int kf = 0; kf < 4; kf++) {                                                           \
            int sw = lrs ^ (kf * 2);                                                               \
            bf16x8 a0 = *(const bf16x8*)&(KcP)[(kf * 16 + lr) * 64 + ((hg ^ sw) << 3)];            \
            bf16x8 a1 = *(const bf16x8*)&(KcP)[(kf * 16 + lr) * 64 + (((4 + hg) ^ sw) << 3)];      \
            st[kf] = mfma16(a1, qf1, mfma16(a0, qf0, (floatx4)0.f));                               \
        }                                                                                          \
        bool rightC = (key0 > q0 + 159);                                                           \
        bool leftC = (key0 + 95 < q0);                                                             \
        float cbv = rightC ? rpl64 : rpl0;                                                         \
        float sv[16];                                                                              \
        float mx = -1e30f;                                                                         \
        if (leftC || rightC) {                                                                     \
            _Pragma("unroll")                                                                      \
            for (int kf = 0; kf < 4; kf++)                                                         \
                _Pragma("unroll")                                                                  \
                for (int r = 0; r < 4; r++) {                                                      \
                    float v = st[kf][r] * scale + cbv;                                             \
                    sv[kf * 4 + r] = v;                                                            \
                    mx = fmaxf(mx, v);                                                             \
                }                                                                                  \
        } else {                                                                                   \
            _Pragma("unroll")                                                                      \
            for (int kf = 0; kf < 4; kf++)                                                         \
                _Pragma("unroll")                                                                  \
                for (int r = 0; r < 4; r++) {                                                      \
                    int rel = key0 + kf * 16 + hg * 4 + r - qi;                                    \
                    rel = rel < -MAXD ? -MAXD : (rel > MAXD ? MAXD : rel);                         \
                    float v = st[kf][r] * scale + rpl[rel + MAXD];                                 \
                    sv[kf * 4 + r] = v;                                                            \
                    mx = fmaxf(mx, v);                                                             \
                }                                                                                  \
        }                                                                                          \
        mx = fmaxf(mx, __shfl_xor(mx, 16, 64));                                                    \
        mx = fmaxf(mx, __shfl_xor(mx, 32, 64));                                                    \
        float newm = fmaxf(mst, mx);                                                               \
        float corr = __expf(mst - newm);                                                           \
        mst = newm;                                                                                \
        float ps = 0.f;                                                                            \
        unsigned int pk[8];                                                                        \
        _Pragma("unroll")                                                                          \
        for (int kf = 0; kf < 4; kf++)                                                             \
            _Pragma("unroll")                                                                      \
            for (int j = 0; j < 2; j++) {                                                          \
                float p0 = __expf(sv[kf * 4 + 2 * j] - newm);                                      \
                float p1 = __expf(sv[kf * 4 + 2 * j + 1] - newm);                                  \
                ps += p0 + p1;                                                                     \
                pk[kf * 2 + j] = (unsigned int)f2bf(p0) | ((unsigned int)f2bf(p1) << 16);          \
            }                                                                                      \
        lst = lst * corr + ps;                                                                     \
        _Pragma("unroll")                                                                          \
        for (int df = 0; df < 4; df++) o[df] *= corr;                                              \
        _Pragma("unroll")                                                                          \
        for (int kf = 0; kf < 4; kf++)                                                             \
            _Pragma("unroll")                                                                      \
            for (int j = 0; j < 2; j++) {                                                          \
                int ch = ((kf * 2 + (hg >> 1)) ^ lrs) & 7;                                         \
                *(unsigned int*)&PsW[lr * 64 + (ch << 3) + (hg & 1) * 4 + 2 * j] = pk[kf * 2 + j]; \
            }                                                                                      \
        _Pragma("unroll")                                                                          \
        for (int e = 0; e < 8; e++) {                                                              \
            int d = kch * 8 + e;                                                                   \
            int ch = ((kr >> 3) ^ e ^ kch) & 7;                                                    \
            unsigned short val = (unsigned short)(((const unsigned int*)&tv)[e >> 1] >>            \
                                                  ((e & 1) * 16));                                 \
            Vt[d * 64 + (ch << 3) + (kr & 7)] = val;                                               \
        }                                                                                          \
        __syncthreads();                                                                           \
        bf16x8 pb0 = *(const bf16x8*)&PsW[lr * 64 + ((hg ^ lrs) << 3)];                            \
        bf16x8 pb1 = *(const bf16x8*)&PsW[lr * 64 + (((4 + hg) ^ lrs) << 3)];                      \
        _Pragma("unroll")                                                                          \
        for (int df = 0; df < 4; df++) {                                                           \
            int sw = lrs ^ (df * 2);                                                               \
            bf16x8 v0 = *(const bf16x8*)&Vt[(df * 16 + lr) * 64 + ((hg ^ sw) << 3)];               \
            bf16x8 v1 = *(const bf16x8*)&Vt[(df * 16 + lr) * 64 + (((4 + hg) ^ sw) << 3)];         \
            o[df] = mfma16(v1, pb1, mfma16(v0, pb0, o[df]));                                       \
        }                                                                                          \
        __syncthreads();                                                                           \
    }

    for (int kt = 0; kt < L_ / 64; kt += 2) {
        ATT_STEP(kt, Kb0, kdst1, true);
        ATT_STEP(kt + 1, Kb1, kdst0, (kt + 2 < L_ / 64));
    }
#undef ATT_STEP

    float rs = lst;
    rs += __shfl_xor(rs, 16, 64);
    rs += __shfl_xor(rs, 32, 64);
    float inv = 1.f / rs;
    size_t obase = (size_t)(b * L_ + qi) * 1024 + hcol;
#pragma unroll
    for (int df = 0; df < 4; df++)
#pragma unroll
        for (int r = 0; r < 4; r++)
            ctx[obase + df * 16 + hg * 4 + r] = f2bf(o[df][r] * inv);
}

// ---------------- fused residual + layernorm ----------------
template <bool WBF>
__global__ __launch_bounds__(256) void resln_kernel(const float* __restrict__ ra,
                                                    const float* __restrict__ rb,
                                                    const float* __restrict__ g,
                                                    const float* __restrict__ be,
                                                    float* __restrict__ outf,
                                                    unsigned short* __restrict__ outb) {
    __shared__ float red[4];
    __shared__ float red2[4];
    int row = blockIdx.x;
    int t = threadIdx.x;
    int w = t >> 6, lane = t & 63;
    size_t base = (size_t)row * 1024 + t * 4;
    floatx4 a = *(const floatx4*)&ra[base];
    floatx4 b = *(const floatx4*)&rb[base];
    floatx4 y = a + b;
    float s = y[0] + y[1] + y[2] + y[3];
#pragma unroll
    for (int d = 1; d < 64; d <<= 1) s += __shfl_xor(s, d, 64);
    if (lane == 0) red[w] = s;
    __syncthreads();
    float mu = (red[0] + red[1] + red[2] + red[3]) * (1.f / 1024.f);
    floatx4 d4 = y - mu;
    float sq = d4[0] * d4[0] + d4[1] * d4[1] + d4[2] * d4[2] + d4[3] * d4[3];
#pragma unroll
    for (int d = 1; d < 64; d <<= 1) sq += __shfl_xor(sq, d, 64);
    if (lane == 0) red2[w] = sq;
    __syncthreads();
    float var = (red2[0] + red2[1] + red2[2] + red2[3]) * (1.f / 1024.f);
    float rstd = rsqrtf(var + 1e-5f);
    floatx4 gg = *(const floatx4*)&g[t * 4];
    floatx4 bb = *(const floatx4*)&be[t * 4];
    floatx4 outv;
#pragma unroll
    for (int i = 0; i < 4; i++) outv[i] = d4[i] * rstd * gg[i] + bb[i];
    *(floatx4*)&outf[base] = outv;
    if (WBF) {
        ushort4v ov;
        ov.x = f2bf(outv[0]); ov.y = f2bf(outv[1]); ov.z = f2bf(outv[2]); ov.w = f2bf(outv[3]);
        *(ushort4v*)&outb[base] = ov;
    }
}

extern "C" void kernel_launch(void* const* d_in, const int* in_sizes, int n_in,
                              void* d_out, int out_size, void* d_ws, size_t ws_size,
                              hipStream_t stream) {
    const float* src = (const float*)d_in[0];
    const float* Wq = (const float*)d_in[1];
    const float* Wk = (const float*)d_in[2];
    const float* Wv = (const float*)d_in[3];
    const float* bq = (const float*)d_in[4];
    const float* bk = (const float*)d_in[5];
    const float* bv = (const float*)d_in[6];
    const float* Wo = (const float*)d_in[7];
    const float* bo = (const float*)d_in[8];
    const float* rpe = (const float*)d_in[9];
    const float* W1 = (const float*)d_in[10];
    const float* b1 = (const float*)d_in[11];
    const float* W2 = (const float*)d_in[12];
    const float* b2 = (const float*)d_in[13];
    const float* ln1g = (const float*)d_in[14];
    const float* ln1b = (const float*)d_in[15];
    const float* ln2g = (const float*)d_in[16];
    const float* ln2b = (const float*)d_in[17];
    float* out = (float*)d_out;
    char* ws = (char*)d_ws;

    const size_t o_srcb = 0;                       // 8 MB   bf16 src; later reused as xb
    const size_t o_wtqkv = o_srcb + 8388608;       // 6 MB
    const size_t o_wto = o_wtqkv + 6291456;        // 2 MB
    const size_t o_wt1 = o_wto + 2097152;          // 8 MB
    const size_t o_wt2 = o_wt1 + 8388608;          // 8 MB
    const size_t o_bqkv = o_wt2 + 8388608;         // 12 KB
    const size_t o_qkv = o_bqkv + 12288;           // 24 MB  qkv bf16; later reused as attnout/ff fp32
    const size_t o_ctxb = o_qkv + 25165824;        // 8 MB
    const size_t o_x = o_ctxb + 8388608;           // 16 MB
    const size_t o_hb = o_x + 16777216;            // 32 MB

    unsigned short* srcb = (unsigned short*)(ws + o_srcb);
    unsigned short* wtqkv = (unsigned short*)(ws + o_wtqkv);
    unsigned short* wto = (unsigned short*)(ws + o_wto);
    unsigned short* wt1 = (unsigned short*)(ws + o_wt1);
    unsigned short* wt2 = (unsigned short*)(ws + o_wt2);
    float* bqkv = (float*)(ws + o_bqkv);
    unsigned short* qkvb = (unsigned short*)(ws + o_qkv);
    unsigned short* ctxb = (unsigned short*)(ws + o_ctxb);
    float* x = (float*)(ws + o_x);
    unsigned short* hb = (unsigned short*)(ws + o_hb);
    float* attnout = (float*)(ws + o_qkv);
    float* ff = (float*)(ws + o_qkv);
    unsigned short* xb = (unsigned short*)(ws + o_srcb);

    cast_bf16_kernel<<<4096, 256, 0, stream>>>(src, srcb, 1048576);
    transpose_cast_kernel<<<dim3(32, 32), 256, 0, stream>>>(Wq, wtqkv, 1024, 1024);
    transpose_cast_kernel<<<dim3(32, 32), 256, 0, stream>>>(Wk, wtqkv + 1024 * 1024, 1024, 1024);
    transpose_cast_kernel<<<dim3(32, 32), 256, 0, stream>>>(Wv, wtqkv + 2 * 1024 * 1024, 1024, 1024);
    transpose_cast_kernel<<<dim3(32, 32), 256, 0, stream>>>(Wo, wto, 1024, 1024);
    transpose_cast_kernel<<<dim3(128, 32), 256, 0, stream>>>(W1, wt1, 1024, 4096);
    transpose_cast_kernel<<<dim3(32, 128), 256, 0, stream>>>(W2, wt2, 4096, 1024);
    pack_bias_kernel<<<12, 256, 0, stream>>>(bq, bk, bv, bqkv);

    gemm_kernel<4, true, false><<<768, 256, 0, stream>>>(srcb, wtqkv, bqkv, qkvb, NROW, 3072, 1024, 24);
    attn_kernel<<<512, 512, 0, stream>>>(qkvb, rpe, ctxb);
    gemm_kernel<2, false, false><<<512, 256, 0, stream>>>(ctxb, wto, bo, attnout, NROW, 1024, 1024, 16);
    resln_kernel<true><<<4096, 256, 0, stream>>>(src, attnout, ln1g, ln1b, x, xb);
    gemm_kernel<4, true, true><<<1024, 256, 0, stream>>>(xb, wt1, b1, hb, NROW, 4096, 1024, 32);
    gemm_kernel<2, false, false><<<512, 256, 0, stream>>>(hb, wt2, b2, ff, NROW, 1024, 4096, 16);
    resln_kernel<false><<<4096, 256, 0, stream>>>(x, ff, ln2g, ln2b, out, nullptr);
}